// Round 3
// baseline (330.437 us; speedup 1.0000x reference)
//
#include <hip/hip_runtime.h>
#include <hip/hip_bf16.h>
#include <math.h>

// GateFusion via bf16 MFMA (16x16x32), all-register, persistent grid-stride
// waves with register-prefetch software pipeline + nontemporal stores.
// out = g * (x_d@W_d) + (1-g) * (x_c@W_c),
// g = sigmoid( relu(LN(concat@Wg1)) @ Wg2 ),  per row.
//
// d_ws: fragment-linear bf16 weights (see convert_weights).

namespace {

typedef __attribute__((ext_vector_type(8))) short short8;
typedef __attribute__((ext_vector_type(4))) float f32x4;

constexpr int CD = 64, CC = 96, CH = 64, CF = 128;
constexpr int NFG1 = 20;   // gate-weight frags
constexpr int NFCB = 40;   // combined-output-weight frags

__device__ inline short bf16_of(float f) {
  __hip_bfloat16 h = __float2bfloat16(f);
  return *reinterpret_cast<short*>(&h);
}

__global__ void convert_weights(const float* __restrict__ Wd,
                                const float* __restrict__ Wc,
                                const float* __restrict__ Wg1,
                                short* __restrict__ ws) {
  const int t = blockIdx.x * 256 + threadIdx.x;
  if (t >= 64 * (NFG1 + NFCB)) return;
  const int frag = t >> 6, l = t & 63;
  const int cidx = l & 15, kb = l >> 4;
  float v[8];
  if (frag < NFG1) {
    const int ks = frag >> 2, nt = frag & 3;
    const int n = nt * 16 + cidx, k0 = ks * 32 + kb * 8;
    #pragma unroll
    for (int j = 0; j < 8; ++j) v[j] = Wg1[(k0 + j) * CH + n];
  } else {
    const int f2 = frag - NFG1;
    const int ks = f2 >> 3, nt = f2 & 7;
    const int n = nt * 16 + cidx, k0 = ks * 32 + kb * 8;
    #pragma unroll
    for (int j = 0; j < 8; ++j) {
      const int k = k0 + j;
      v[j] = (k < CD) ? Wd[k * CF + n] : Wc[(k - CD) * CF + n];
    }
  }
  short8 o;
  #pragma unroll
  for (int j = 0; j < 8; ++j) o[j] = bf16_of(v[j]);
  *reinterpret_cast<short8*>(ws + frag * 512 + l * 8) = o;
}

__global__ __launch_bounds__(256, 2)
void gate_fusion_mfma(const float* __restrict__ xd,
                      const float* __restrict__ xc,
                      const float* __restrict__ gma,
                      const float* __restrict__ bta,
                      const float* __restrict__ Wg2,
                      const short* __restrict__ wf,
                      float* __restrict__ out,
                      int nTiles, int nWaves) {
  const int lane = threadIdx.x & 63;
  const int wgid = blockIdx.x * 4 + (threadIdx.x >> 6);
  const int cidx = lane & 15;
  const int kb   = lane >> 4;

  // per-wave constants (L2-hit loads, once)
  float gmv[4], btv[4], w2v[4];
  #pragma unroll
  for (int nt = 0; nt < 4; ++nt) {
    const int c = nt * 16 + cidx;
    gmv[nt] = gma[c]; btv[nt] = bta[c]; w2v[nt] = Wg2[c];
  }

  const f32x4 vzero = {0.f, 0.f, 0.f, 0.f};
  f32x4 buf[2][5][2];   // raw f32 for one 32-row tile (80 VGPR)

  // ---- prologue: load first tile
  int t = wgid;
  if (t >= nTiles) return;
  {
    #pragma unroll
    for (int mt = 0; mt < 2; ++mt) {
      const size_t row = (size_t)t * 32 + mt * 16 + cidx;
      const float* rd = xd + row * CD + kb * 8;
      const float* rc = xc + row * CC + kb * 8;
      #pragma unroll
      for (int ks = 0; ks < 5; ++ks) {
        const float* p = (ks < 2) ? (rd + ks * 32) : (rc + (ks - 2) * 32);
        buf[mt][ks][0] = *reinterpret_cast<const f32x4*>(p);
        buf[mt][ks][1] = *reinterpret_cast<const f32x4*>(p + 4);
      }
    }
  }

  for (; t < nTiles; t += nWaves) {
    // ---- convert buf -> bf16 A-fragments (buf dead afterwards)
    short8 xf[2][5];
    #pragma unroll
    for (int mt = 0; mt < 2; ++mt)
      #pragma unroll
      for (int ks = 0; ks < 5; ++ks) {
        short8 f;
        #pragma unroll
        for (int j = 0; j < 4; ++j) {
          f[j]     = bf16_of(buf[mt][ks][0][j]);
          f[4 + j] = bf16_of(buf[mt][ks][1][j]);
        }
        xf[mt][ks] = f;
      }

    // ---- issue next tile's loads into buf (hides HBM latency under compute)
    const int tn = t + nWaves;
    if (tn < nTiles) {
      #pragma unroll
      for (int mt = 0; mt < 2; ++mt) {
        const size_t row = (size_t)tn * 32 + mt * 16 + cidx;
        const float* rd = xd + row * CD + kb * 8;
        const float* rc = xc + row * CC + kb * 8;
        #pragma unroll
        for (int ks = 0; ks < 5; ++ks) {
          const float* p = (ks < 2) ? (rd + ks * 32) : (rc + (ks - 2) * 32);
          buf[mt][ks][0] = *reinterpret_cast<const f32x4*>(p);
          buf[mt][ks][1] = *reinterpret_cast<const f32x4*>(p + 4);
        }
      }
    }

    // ---- phase 1: h = concat @ Wg1  [32 x 64]
    f32x4 acc1[2][4];
    #pragma unroll
    for (int mt = 0; mt < 2; ++mt)
      #pragma unroll
      for (int nt = 0; nt < 4; ++nt) acc1[mt][nt] = vzero;

    #pragma unroll
    for (int ks = 0; ks < 5; ++ks) {
      short8 bg[4];
      #pragma unroll
      for (int nt = 0; nt < 4; ++nt)
        bg[nt] = *reinterpret_cast<const short8*>(wf + (ks * 4 + nt) * 512 + lane * 8);
      #pragma unroll
      for (int mt = 0; mt < 2; ++mt)
        #pragma unroll
        for (int nt = 0; nt < 4; ++nt)
          acc1[mt][nt] = __builtin_amdgcn_mfma_f32_16x16x32_bf16(
              xf[mt][ks], bg[nt], acc1[mt][nt], 0, 0, 0);
    }

    // ---- LayerNorm + relu + dot(Wg2) + sigmoid (C-fragment layout)
    float gate[2][4];
    #pragma unroll
    for (int mt = 0; mt < 2; ++mt) {
      float s[4], q[4];
      #pragma unroll
      for (int r = 0; r < 4; ++r) {
        s[r] = 0.f; q[r] = 0.f;
        #pragma unroll
        for (int nt = 0; nt < 4; ++nt) {
          const float c = acc1[mt][nt][r];
          s[r] += c; q[r] += c * c;
        }
      }
      #pragma unroll
      for (int m = 1; m < 16; m <<= 1)
        #pragma unroll
        for (int r = 0; r < 4; ++r) {
          s[r] += __shfl_xor(s[r], m, 64);
          q[r] += __shfl_xor(q[r], m, 64);
        }
      float p[4];
      #pragma unroll
      for (int r = 0; r < 4; ++r) {
        const float mu  = s[r] * (1.f / CH);
        const float var = q[r] * (1.f / CH) - mu * mu;
        const float rsd = rsqrtf(var + 1e-5f);
        float pp = 0.f;
        #pragma unroll
        for (int nt = 0; nt < 4; ++nt) {
          const float h = fmaxf((acc1[mt][nt][r] - mu) * rsd * gmv[nt] + btv[nt], 0.f);
          pp += h * w2v[nt];
        }
        p[r] = pp;
      }
      #pragma unroll
      for (int m = 1; m < 16; m <<= 1)
        #pragma unroll
        for (int r = 0; r < 4; ++r) p[r] += __shfl_xor(p[r], m, 64);
      #pragma unroll
      for (int r = 0; r < 4; ++r) gate[mt][r] = 1.f / (1.f + expf(-p[r]));
    }

    // ---- phase 2 in 4 nt-quarter slices: dual D/C accumulate, blend, NT store
    const short* wcb = wf + NFG1 * 512;
    #pragma unroll
    for (int q = 0; q < 4; ++q) {
      f32x4 aD[2][2], aC[2][2];
      #pragma unroll
      for (int mt = 0; mt < 2; ++mt)
        #pragma unroll
        for (int nt = 0; nt < 2; ++nt) { aD[mt][nt] = vzero; aC[mt][nt] = vzero; }

      #pragma unroll
      for (int ks = 0; ks < 5; ++ks) {
        short8 bg[2];
        #pragma unroll
        for (int nt = 0; nt < 2; ++nt)
          bg[nt] = *reinterpret_cast<const short8*>(
              wcb + (ks * 8 + q * 2 + nt) * 512 + lane * 8);
        if (ks < 2) {
          #pragma unroll
          for (int mt = 0; mt < 2; ++mt)
            #pragma unroll
            for (int nt = 0; nt < 2; ++nt)
              aD[mt][nt] = __builtin_amdgcn_mfma_f32_16x16x32_bf16(
                  xf[mt][ks], bg[nt], aD[mt][nt], 0, 0, 0);
        } else {
          #pragma unroll
          for (int mt = 0; mt < 2; ++mt)
            #pragma unroll
            for (int nt = 0; nt < 2; ++nt)
              aC[mt][nt] = __builtin_amdgcn_mfma_f32_16x16x32_bf16(
                  xf[mt][ks], bg[nt], aC[mt][nt], 0, 0, 0);
        }
      }

      #pragma unroll
      for (int mt = 0; mt < 2; ++mt) {
        const size_t rowb = (size_t)t * 32 + mt * 16 + kb * 4;
        #pragma unroll
        for (int nt = 0; nt < 2; ++nt) {
          #pragma unroll
          for (int r = 0; r < 4; ++r) {
            const float g = gate[mt][r];
            const float o = g * aD[mt][nt][r] + (1.f - g) * aC[mt][nt][r];
            __builtin_nontemporal_store(
                o, &out[(rowb + r) * CF + (q * 2 + nt) * 16 + cidx]);
          }
        }
      }
    }
  }
}

}  // namespace

extern "C" void kernel_launch(void* const* d_in, const int* in_sizes, int n_in,
                              void* d_out, int out_size, void* d_ws, size_t ws_size,
                              hipStream_t stream) {
  const float* xd  = (const float*)d_in[0];
  const float* xc  = (const float*)d_in[1];
  const float* Wd  = (const float*)d_in[2];
  const float* Wc  = (const float*)d_in[3];
  const float* Wg1 = (const float*)d_in[4];
  const float* gma = (const float*)d_in[5];
  const float* bta = (const float*)d_in[6];
  const float* Wg2 = (const float*)d_in[7];
  float* out = (float*)d_out;
  short* ws  = (short*)d_ws;   // needs 60 KB

  const int N = in_sizes[0] / CD;

  convert_weights<<<dim3(15), dim3(256), 0, stream>>>(Wd, Wc, Wg1, ws);

  const int nTiles = N / 32;            // N % 32 == 0 for this problem
  const int nBlocks = 1024;             // 4096 persistent waves
  const int nWaves  = nBlocks * 4;
  gate_fusion_mfma<<<dim3(nBlocks), dim3(256), 0, stream>>>(
      xd, xc, gma, bta, Wg2, ws, out, nTiles, nWaves);
}

// Round 4
// 327.095 us; speedup vs baseline: 1.0102x; 1.0102x over previous
//
#include <hip/hip_runtime.h>
#include <hip/hip_bf16.h>
#include <math.h>

// GateFusion via bf16 MFMA (16x16x32), all-register, persistent grid-stride
// waves with register-prefetch software pipeline. Plain cached stores
// (NT stores caused partial-line RMW at HBM: WRITE 250->725MB, FETCH 157->533MB).
// out = g * (x_d@W_d) + (1-g) * (x_c@W_c),
// g = sigmoid( relu(LN(concat@Wg1)) @ Wg2 ),  per row.
//
// d_ws: fragment-linear bf16 weights (see convert_weights).

namespace {

typedef __attribute__((ext_vector_type(8))) short short8;
typedef __attribute__((ext_vector_type(4))) float f32x4;

constexpr int CD = 64, CC = 96, CH = 64, CF = 128;
constexpr int NFG1 = 20;   // gate-weight frags
constexpr int NFCB = 40;   // combined-output-weight frags

__device__ inline short bf16_of(float f) {
  __hip_bfloat16 h = __float2bfloat16(f);
  return *reinterpret_cast<short*>(&h);
}

__global__ void convert_weights(const float* __restrict__ Wd,
                                const float* __restrict__ Wc,
                                const float* __restrict__ Wg1,
                                short* __restrict__ ws) {
  const int t = blockIdx.x * 256 + threadIdx.x;
  if (t >= 64 * (NFG1 + NFCB)) return;
  const int frag = t >> 6, l = t & 63;
  const int cidx = l & 15, kb = l >> 4;
  float v[8];
  if (frag < NFG1) {
    const int ks = frag >> 2, nt = frag & 3;
    const int n = nt * 16 + cidx, k0 = ks * 32 + kb * 8;
    #pragma unroll
    for (int j = 0; j < 8; ++j) v[j] = Wg1[(k0 + j) * CH + n];
  } else {
    const int f2 = frag - NFG1;
    const int ks = f2 >> 3, nt = f2 & 7;
    const int n = nt * 16 + cidx, k0 = ks * 32 + kb * 8;
    #pragma unroll
    for (int j = 0; j < 8; ++j) {
      const int k = k0 + j;
      v[j] = (k < CD) ? Wd[k * CF + n] : Wc[(k - CD) * CF + n];
    }
  }
  short8 o;
  #pragma unroll
  for (int j = 0; j < 8; ++j) o[j] = bf16_of(v[j]);
  *reinterpret_cast<short8*>(ws + frag * 512 + l * 8) = o;
}

__global__ __launch_bounds__(256, 2)
void gate_fusion_mfma(const float* __restrict__ xd,
                      const float* __restrict__ xc,
                      const float* __restrict__ gma,
                      const float* __restrict__ bta,
                      const float* __restrict__ Wg2,
                      const short* __restrict__ wf,
                      float* __restrict__ out,
                      int nTiles, int nWaves) {
  const int lane = threadIdx.x & 63;
  const int wgid = blockIdx.x * 4 + (threadIdx.x >> 6);
  const int cidx = lane & 15;
  const int kb   = lane >> 4;

  // per-wave constants (L2-hit loads, once)
  float gmv[4], btv[4], w2v[4];
  #pragma unroll
  for (int nt = 0; nt < 4; ++nt) {
    const int c = nt * 16 + cidx;
    gmv[nt] = gma[c]; btv[nt] = bta[c]; w2v[nt] = Wg2[c];
  }

  const f32x4 vzero = {0.f, 0.f, 0.f, 0.f};
  f32x4 buf[2][5][2];   // raw f32 for one 32-row tile (80 VGPR)

  // ---- prologue: load first tile
  int t = wgid;
  if (t >= nTiles) return;
  {
    #pragma unroll
    for (int mt = 0; mt < 2; ++mt) {
      const size_t row = (size_t)t * 32 + mt * 16 + cidx;
      const float* rd = xd + row * CD + kb * 8;
      const float* rc = xc + row * CC + kb * 8;
      #pragma unroll
      for (int ks = 0; ks < 5; ++ks) {
        const float* p = (ks < 2) ? (rd + ks * 32) : (rc + (ks - 2) * 32);
        buf[mt][ks][0] = *reinterpret_cast<const f32x4*>(p);
        buf[mt][ks][1] = *reinterpret_cast<const f32x4*>(p + 4);
      }
    }
  }

  for (; t < nTiles; t += nWaves) {
    // ---- convert buf -> bf16 A-fragments (buf dead afterwards)
    short8 xf[2][5];
    #pragma unroll
    for (int mt = 0; mt < 2; ++mt)
      #pragma unroll
      for (int ks = 0; ks < 5; ++ks) {
        short8 f;
        #pragma unroll
        for (int j = 0; j < 4; ++j) {
          f[j]     = bf16_of(buf[mt][ks][0][j]);
          f[4 + j] = bf16_of(buf[mt][ks][1][j]);
        }
        xf[mt][ks] = f;
      }

    // ---- issue next tile's loads into buf (hides HBM latency under compute)
    const int tn = t + nWaves;
    if (tn < nTiles) {
      #pragma unroll
      for (int mt = 0; mt < 2; ++mt) {
        const size_t row = (size_t)tn * 32 + mt * 16 + cidx;
        const float* rd = xd + row * CD + kb * 8;
        const float* rc = xc + row * CC + kb * 8;
        #pragma unroll
        for (int ks = 0; ks < 5; ++ks) {
          const float* p = (ks < 2) ? (rd + ks * 32) : (rc + (ks - 2) * 32);
          buf[mt][ks][0] = *reinterpret_cast<const f32x4*>(p);
          buf[mt][ks][1] = *reinterpret_cast<const f32x4*>(p + 4);
        }
      }
    }

    // ---- phase 1: h = concat @ Wg1  [32 x 64]
    f32x4 acc1[2][4];
    #pragma unroll
    for (int mt = 0; mt < 2; ++mt)
      #pragma unroll
      for (int nt = 0; nt < 4; ++nt) acc1[mt][nt] = vzero;

    #pragma unroll
    for (int ks = 0; ks < 5; ++ks) {
      short8 bg[4];
      #pragma unroll
      for (int nt = 0; nt < 4; ++nt)
        bg[nt] = *reinterpret_cast<const short8*>(wf + (ks * 4 + nt) * 512 + lane * 8);
      #pragma unroll
      for (int mt = 0; mt < 2; ++mt)
        #pragma unroll
        for (int nt = 0; nt < 4; ++nt)
          acc1[mt][nt] = __builtin_amdgcn_mfma_f32_16x16x32_bf16(
              xf[mt][ks], bg[nt], acc1[mt][nt], 0, 0, 0);
    }

    // ---- LayerNorm + relu + dot(Wg2) + sigmoid (C-fragment layout)
    float gate[2][4];
    #pragma unroll
    for (int mt = 0; mt < 2; ++mt) {
      float s[4], q[4];
      #pragma unroll
      for (int r = 0; r < 4; ++r) {
        s[r] = 0.f; q[r] = 0.f;
        #pragma unroll
        for (int nt = 0; nt < 4; ++nt) {
          const float c = acc1[mt][nt][r];
          s[r] += c; q[r] += c * c;
        }
      }
      #pragma unroll
      for (int m = 1; m < 16; m <<= 1)
        #pragma unroll
        for (int r = 0; r < 4; ++r) {
          s[r] += __shfl_xor(s[r], m, 64);
          q[r] += __shfl_xor(q[r], m, 64);
        }
      float p[4];
      #pragma unroll
      for (int r = 0; r < 4; ++r) {
        const float mu  = s[r] * (1.f / CH);
        const float var = q[r] * (1.f / CH) - mu * mu;
        const float rsd = rsqrtf(var + 1e-5f);
        float pp = 0.f;
        #pragma unroll
        for (int nt = 0; nt < 4; ++nt) {
          const float h = fmaxf((acc1[mt][nt][r] - mu) * rsd * gmv[nt] + btv[nt], 0.f);
          pp += h * w2v[nt];
        }
        p[r] = pp;
      }
      #pragma unroll
      for (int m = 1; m < 16; m <<= 1)
        #pragma unroll
        for (int r = 0; r < 4; ++r) p[r] += __shfl_xor(p[r], m, 64);
      #pragma unroll
      for (int r = 0; r < 4; ++r) gate[mt][r] = 1.f / (1.f + expf(-p[r]));
    }

    // ---- phase 2 in 4 nt-quarter slices: dual D/C accumulate, blend, store
    const short* wcb = wf + NFG1 * 512;
    #pragma unroll
    for (int q = 0; q < 4; ++q) {
      f32x4 aD[2][2], aC[2][2];
      #pragma unroll
      for (int mt = 0; mt < 2; ++mt)
        #pragma unroll
        for (int nt = 0; nt < 2; ++nt) { aD[mt][nt] = vzero; aC[mt][nt] = vzero; }

      #pragma unroll
      for (int ks = 0; ks < 5; ++ks) {
        short8 bg[2];
        #pragma unroll
        for (int nt = 0; nt < 2; ++nt)
          bg[nt] = *reinterpret_cast<const short8*>(
              wcb + (ks * 8 + q * 2 + nt) * 512 + lane * 8);
        if (ks < 2) {
          #pragma unroll
          for (int mt = 0; mt < 2; ++mt)
            #pragma unroll
            for (int nt = 0; nt < 2; ++nt)
              aD[mt][nt] = __builtin_amdgcn_mfma_f32_16x16x32_bf16(
                  xf[mt][ks], bg[nt], aD[mt][nt], 0, 0, 0);
        } else {
          #pragma unroll
          for (int mt = 0; mt < 2; ++mt)
            #pragma unroll
            for (int nt = 0; nt < 2; ++nt)
              aC[mt][nt] = __builtin_amdgcn_mfma_f32_16x16x32_bf16(
                  xf[mt][ks], bg[nt], aC[mt][nt], 0, 0, 0);
        }
      }

      #pragma unroll
      for (int mt = 0; mt < 2; ++mt) {
        const size_t rowb = (size_t)t * 32 + mt * 16 + kb * 4;
        #pragma unroll
        for (int nt = 0; nt < 2; ++nt) {
          #pragma unroll
          for (int r = 0; r < 4; ++r) {
            const float g = gate[mt][r];
            const float o = g * aD[mt][nt][r] + (1.f - g) * aC[mt][nt][r];
            out[(rowb + r) * CF + (q * 2 + nt) * 16 + cidx] = o;
          }
        }
      }
    }
  }
}

}  // namespace

extern "C" void kernel_launch(void* const* d_in, const int* in_sizes, int n_in,
                              void* d_out, int out_size, void* d_ws, size_t ws_size,
                              hipStream_t stream) {
  const float* xd  = (const float*)d_in[0];
  const float* xc  = (const float*)d_in[1];
  const float* Wd  = (const float*)d_in[2];
  const float* Wc  = (const float*)d_in[3];
  const float* Wg1 = (const float*)d_in[4];
  const float* gma = (const float*)d_in[5];
  const float* bta = (const float*)d_in[6];
  const float* Wg2 = (const float*)d_in[7];
  float* out = (float*)d_out;
  short* ws  = (short*)d_ws;   // needs 60 KB

  const int N = in_sizes[0] / CD;

  convert_weights<<<dim3(15), dim3(256), 0, stream>>>(Wd, Wc, Wg1, ws);

  const int nTiles = N / 32;            // N % 32 == 0 for this problem
  const int nBlocks = 1024;             // 4096 persistent waves
  const int nWaves  = nBlocks * 4;
  gate_fusion_mfma<<<dim3(nBlocks), dim3(256), 0, stream>>>(
      xd, xc, gma, bta, Wg2, ws, out, nTiles, nWaves);
}

// Round 5
// 139.366 us; speedup vs baseline: 2.3710x; 2.3470x over previous
//
#include <hip/hip_runtime.h>
#include <hip/hip_bf16.h>
#include <math.h>

// GateFusion via bf16 MFMA (16x16x32). Round-2 proven structure (one 256-row
// tile per block, exact HBM traffic) + weights staged in LDS once per block
// (round 2 re-read 60KB/wave/tile from L2 on the MFMA critical path).
// out = g * (x_d@W_d) + (1-g) * (x_c@W_c),
// g = sigmoid( relu(LN(concat@Wg1)) @ Wg2 ),  per row.
//
// d_ws: fragment-linear bf16 weights (see convert_weights):
//   frags 0..19 : Wg1  (ks 0..4) x (nt 0..3)   [K=160, N=64]
//   frags 20..59: [Wd;Wc] (ks 0..4) x (nt 0..7) [K=160, N=128]
// frag = 512 bf16: lane l holds B[k0+j][n], k0=ks*32+(l>>4)*8, n=nt*16+(l&15).

namespace {

typedef __attribute__((ext_vector_type(8))) short short8;
typedef __attribute__((ext_vector_type(4))) float f32x4;

constexpr int CD = 64, CC = 96, CH = 64, CF = 128;
constexpr int NFG1 = 20;   // gate-weight frags
constexpr int NFCB = 40;   // combined-output-weight frags
constexpr int NFRAG = NFG1 + NFCB;           // 60 frags = 61440 B
constexpr int WCHUNKS = NFRAG * 512 * 2 / 16; // 3840 x 16B

__device__ inline short bf16_of(float f) {
  __hip_bfloat16 h = __float2bfloat16(f);
  return *reinterpret_cast<short*>(&h);
}

__global__ void convert_weights(const float* __restrict__ Wd,
                                const float* __restrict__ Wc,
                                const float* __restrict__ Wg1,
                                short* __restrict__ ws) {
  const int t = blockIdx.x * 256 + threadIdx.x;
  if (t >= 64 * NFRAG) return;
  const int frag = t >> 6, l = t & 63;
  const int cidx = l & 15, kb = l >> 4;
  float v[8];
  if (frag < NFG1) {
    const int ks = frag >> 2, nt = frag & 3;
    const int n = nt * 16 + cidx, k0 = ks * 32 + kb * 8;
    #pragma unroll
    for (int j = 0; j < 8; ++j) v[j] = Wg1[(k0 + j) * CH + n];
  } else {
    const int f2 = frag - NFG1;
    const int ks = f2 >> 3, nt = f2 & 7;
    const int n = nt * 16 + cidx, k0 = ks * 32 + kb * 8;
    #pragma unroll
    for (int j = 0; j < 8; ++j) {
      const int k = k0 + j;
      v[j] = (k < CD) ? Wd[k * CF + n] : Wc[(k - CD) * CF + n];
    }
  }
  short8 o;
  #pragma unroll
  for (int j = 0; j < 8; ++j) o[j] = bf16_of(v[j]);
  *reinterpret_cast<short8*>(ws + frag * 512 + l * 8) = o;
}

__global__ __launch_bounds__(512, 4)
void gate_fusion_mfma(const float* __restrict__ xd,
                      const float* __restrict__ xc,
                      const float* __restrict__ gma,
                      const float* __restrict__ bta,
                      const float* __restrict__ Wg2,
                      const short* __restrict__ wf,
                      float* __restrict__ out, int N) {
  __shared__ short wlds[NFRAG * 512];

  const int tid  = threadIdx.x;
  const int lane = tid & 63;
  const int wv   = tid >> 6;                 // 0..7
  const int r0   = blockIdx.x * 256 + wv * 32;
  const int cidx = lane & 15;
  const int kb   = lane >> 4;
  const bool active = (r0 < N);              // N % 32 == 0: whole-wave granularity

  // ---- issue this wave's x loads first (in flight under staging+barrier)
  f32x4 buf[2][5][2];
  if (active) {
    #pragma unroll
    for (int mt = 0; mt < 2; ++mt) {
      const size_t row = (size_t)(r0 + mt * 16 + cidx);
      const float* rd = xd + row * CD + kb * 8;
      const float* rc = xc + row * CC + kb * 8;
      #pragma unroll
      for (int ks = 0; ks < 5; ++ks) {
        const float* p = (ks < 2) ? (rd + ks * 32) : (rc + (ks - 2) * 32);
        buf[mt][ks][0] = *reinterpret_cast<const f32x4*>(p);
        buf[mt][ks][1] = *reinterpret_cast<const f32x4*>(p + 4);
      }
    }
  }

  // ---- stage all 60 weight frags (61440 B) into LDS
  for (int c = tid; c < WCHUNKS; c += 512) {
    short8 v = *reinterpret_cast<const short8*>(wf + (size_t)c * 8);
    *reinterpret_cast<short8*>(&wlds[c * 8]) = v;
  }
  __syncthreads();
  if (!active) return;   // after the only barrier

  // per-wave constants (L2-hit loads)
  float gmv[4], btv[4], w2v[4];
  #pragma unroll
  for (int nt = 0; nt < 4; ++nt) {
    const int c = nt * 16 + cidx;
    gmv[nt] = gma[c]; btv[nt] = bta[c]; w2v[nt] = Wg2[c];
  }

  // ---- convert x to bf16 A-fragments
  short8 xf[2][5];
  #pragma unroll
  for (int mt = 0; mt < 2; ++mt)
    #pragma unroll
    for (int ks = 0; ks < 5; ++ks) {
      short8 f;
      #pragma unroll
      for (int j = 0; j < 4; ++j) {
        f[j]     = bf16_of(buf[mt][ks][0][j]);
        f[4 + j] = bf16_of(buf[mt][ks][1][j]);
      }
      xf[mt][ks] = f;
    }

  // ---- phase 1: h = concat @ Wg1  [32 x 64]
  const f32x4 vzero = {0.f, 0.f, 0.f, 0.f};
  f32x4 acc1[2][4];
  #pragma unroll
  for (int mt = 0; mt < 2; ++mt)
    #pragma unroll
    for (int nt = 0; nt < 4; ++nt) acc1[mt][nt] = vzero;

  #pragma unroll
  for (int ks = 0; ks < 5; ++ks) {
    short8 bg[4];
    #pragma unroll
    for (int nt = 0; nt < 4; ++nt)
      bg[nt] = *reinterpret_cast<const short8*>(&wlds[(ks * 4 + nt) * 512 + lane * 8]);
    #pragma unroll
    for (int mt = 0; mt < 2; ++mt)
      #pragma unroll
      for (int nt = 0; nt < 4; ++nt)
        acc1[mt][nt] = __builtin_amdgcn_mfma_f32_16x16x32_bf16(
            xf[mt][ks], bg[nt], acc1[mt][nt], 0, 0, 0);
  }

  // ---- LayerNorm + relu + dot(Wg2) + sigmoid (C-fragment layout)
  float gate[2][4];
  #pragma unroll
  for (int mt = 0; mt < 2; ++mt) {
    float s[4], q[4];
    #pragma unroll
    for (int r = 0; r < 4; ++r) {
      s[r] = 0.f; q[r] = 0.f;
      #pragma unroll
      for (int nt = 0; nt < 4; ++nt) {
        const float c = acc1[mt][nt][r];
        s[r] += c; q[r] += c * c;
      }
    }
    #pragma unroll
    for (int m = 1; m < 16; m <<= 1)
      #pragma unroll
      for (int r = 0; r < 4; ++r) {
        s[r] += __shfl_xor(s[r], m, 64);
        q[r] += __shfl_xor(q[r], m, 64);
      }
    float p[4];
    #pragma unroll
    for (int r = 0; r < 4; ++r) {
      const float mu  = s[r] * (1.f / CH);
      const float var = q[r] * (1.f / CH) - mu * mu;
      const float rsd = rsqrtf(var + 1e-5f);
      float pp = 0.f;
      #pragma unroll
      for (int nt = 0; nt < 4; ++nt) {
        const float h = fmaxf((acc1[mt][nt][r] - mu) * rsd * gmv[nt] + btv[nt], 0.f);
        pp += h * w2v[nt];
      }
      p[r] = pp;
    }
    #pragma unroll
    for (int m = 1; m < 16; m <<= 1)
      #pragma unroll
      for (int r = 0; r < 4; ++r) p[r] += __shfl_xor(p[r], m, 64);
    #pragma unroll
    for (int r = 0; r < 4; ++r) gate[mt][r] = 1.f / (1.f + expf(-p[r]));
  }

  // ---- phase 2 in 4 nt-quarter slices: dual D/C accumulate, blend, store
  #pragma unroll
  for (int q = 0; q < 4; ++q) {
    f32x4 aD[2][2], aC[2][2];
    #pragma unroll
    for (int mt = 0; mt < 2; ++mt)
      #pragma unroll
      for (int nt = 0; nt < 2; ++nt) { aD[mt][nt] = vzero; aC[mt][nt] = vzero; }

    #pragma unroll
    for (int ks = 0; ks < 5; ++ks) {
      short8 bg[2];
      #pragma unroll
      for (int nt = 0; nt < 2; ++nt)
        bg[nt] = *reinterpret_cast<const short8*>(
            &wlds[(NFG1 + ks * 8 + q * 2 + nt) * 512 + lane * 8]);
      if (ks < 2) {
        #pragma unroll
        for (int mt = 0; mt < 2; ++mt)
          #pragma unroll
          for (int nt = 0; nt < 2; ++nt)
            aD[mt][nt] = __builtin_amdgcn_mfma_f32_16x16x32_bf16(
                xf[mt][ks], bg[nt], aD[mt][nt], 0, 0, 0);
      } else {
        #pragma unroll
        for (int mt = 0; mt < 2; ++mt)
          #pragma unroll
          for (int nt = 0; nt < 2; ++nt)
            aC[mt][nt] = __builtin_amdgcn_mfma_f32_16x16x32_bf16(
                xf[mt][ks], bg[nt], aC[mt][nt], 0, 0, 0);
      }
    }

    #pragma unroll
    for (int mt = 0; mt < 2; ++mt) {
      const size_t rowb = (size_t)r0 + mt * 16 + kb * 4;
      #pragma unroll
      for (int nt = 0; nt < 2; ++nt) {
        #pragma unroll
        for (int r = 0; r < 4; ++r) {
          const float g = gate[mt][r];
          const float o = fmaf(g, aD[mt][nt][r] - aC[mt][nt][r], aC[mt][nt][r]);
          out[(rowb + r) * CF + (q * 2 + nt) * 16 + cidx] = o;
        }
      }
    }
  }
}

}  // namespace

extern "C" void kernel_launch(void* const* d_in, const int* in_sizes, int n_in,
                              void* d_out, int out_size, void* d_ws, size_t ws_size,
                              hipStream_t stream) {
  const float* xd  = (const float*)d_in[0];
  const float* xc  = (const float*)d_in[1];
  const float* Wd  = (const float*)d_in[2];
  const float* Wc  = (const float*)d_in[3];
  const float* Wg1 = (const float*)d_in[4];
  const float* gma = (const float*)d_in[5];
  const float* bta = (const float*)d_in[6];
  const float* Wg2 = (const float*)d_in[7];
  float* out = (float*)d_out;
  short* ws  = (short*)d_ws;   // needs 60 KB

  const int N = in_sizes[0] / CD;

  convert_weights<<<dim3(15), dim3(256), 0, stream>>>(Wd, Wc, Wg1, ws);

  const int nblk = (N + 255) / 256;   // 256 rows per 8-wave block
  gate_fusion_mfma<<<dim3(nblk), dim3(512), 0, stream>>>(
      xd, xc, gma, bta, Wg2, ws, out, N);
}